// Round 5
// baseline (171.630 us; speedup 1.0000x reference)
//
#include <hip/hip_runtime.h>
#include <math.h>

#define VOCAB 100000
#define EMB   128
#define BATCH 16384
#define CTX   20
#define NEG   20
#define NSCORE (NEG + 1)   // target + negatives

// softplus(x) = log(1+exp(x)) via raw v_exp_f32/v_log_f32.
// x clamped to [-10,10]; abs err ~1e-5 vs 0.29 absolute threshold.
__device__ __forceinline__ float fast_softplus(float x) {
    return __logf(1.0f + __expf(x));
}

__global__ __launch_bounds__(256, 4) void cbow_loss_kernel(
    const int*   __restrict__ pos_target,     // [B]
    const int*   __restrict__ pos_contexts,   // [B, C]
    const int*   __restrict__ pos_negatives,  // [B, N]
    const float* __restrict__ context_table,  // [VOCAB, 128]
    const float* __restrict__ output_table,   // [VOCAB, 128]
    float*       __restrict__ out)            // [1]
{
    const int tid  = threadIdx.x;
    const int lane = tid & 63;
    const int wave = tid >> 6;          // 0..3

    // ONE ROW PER WAVE, forced wave-uniform so:
    //  - index loads compile to scalar s_load (SGPR result, no shuffles)
    //  - gather addresses are scalar idx<<9 + shared lane*8 (1 VALU/gather)
    const int row = __builtin_amdgcn_readfirstlane(blockIdx.x * 4 + wave);

    const float2* ctab = (const float2*)context_table;  // row stride 64 float2
    const float2* otab = (const float2*)output_table;

    // ---- scalar index loads (contiguous -> s_load_dwordx16 class) ----
    int cidx[CTX], sidx[NSCORE];
#pragma unroll
    for (int c = 0; c < CTX; ++c) cidx[c] = pos_contexts[row * CTX + c];
    sidx[0] = pos_target[row];
#pragma unroll
    for (int n = 0; n < NEG; ++n) sidx[1 + n] = pos_negatives[row * NEG + n];

    // ---- issue ALL 41 row gathers before any consumption. Each is one
    //      fully-coalesced 512B wave instruction (64 lanes x float2).
    //      Consumption order matches issue order, so fine-grained vmcnt
    //      leaves the score loads in flight while ctx is summed. ----
    float2 cv[CTX];
    float2 sv[NSCORE];
#pragma unroll
    for (int c = 0; c < CTX; ++c) cv[c] = ctab[(size_t)cidx[c] * 64 + lane];
#pragma unroll
    for (int n = 0; n < NSCORE; ++n) sv[n] = otab[(size_t)sidx[n] * 64 + lane];

    // ---- context sum (per-lane float2 slice of the 128-d vector) ----
    float2 acc = make_float2(0.f, 0.f);
#pragma unroll
    for (int c = 0; c < CTX; ++c) { acc.x += cv[c].x; acc.y += cv[c].y; }

    // ---- per-lane partial dots ----
    float part[NSCORE];
#pragma unroll
    for (int n = 0; n < NSCORE; ++n)
        part[n] = fmaf(acc.x, sv[n].x, acc.y * sv[n].y);

    // ---- 21 independent 64-lane butterfly reductions (6 steps) ----
#pragma unroll
    for (int s = 32; s >= 1; s >>= 1) {
#pragma unroll
        for (int n = 0; n < NSCORE; ++n) part[n] += __shfl_xor(part[n], s);
    }

    // ---- loss: softplus(-pos) + sum softplus(neg) ----
    float ps = fminf(fmaxf(part[0], -10.f), 10.f);
    float loss = fast_softplus(-ps);
#pragma unroll
    for (int n = 1; n < NSCORE; ++n) {
        float ns = fminf(fmaxf(part[n], -10.f), 10.f);
        loss += fast_softplus(ns);
    }

    // ---- block reduction: 4 wave results -> 1 atomic ----
    __shared__ float sdata[4];
    if (lane == 0) sdata[wave] = loss;
    __syncthreads();
    if (tid == 0) {
        float s = sdata[0] + sdata[1] + sdata[2] + sdata[3];
        atomicAdd(out, s * (1.0f / (float)BATCH));
    }
}

extern "C" void kernel_launch(void* const* d_in, const int* in_sizes, int n_in,
                              void* d_out, int out_size, void* d_ws, size_t ws_size,
                              hipStream_t stream) {
    const int*   pos_target    = (const int*)d_in[0];
    const int*   pos_contexts  = (const int*)d_in[1];
    const int*   pos_negatives = (const int*)d_in[2];
    const float* context_table = (const float*)d_in[3];
    const float* output_table  = (const float*)d_in[4];
    float* out = (float*)d_out;

    // d_out is poisoned 0xAA before every timed launch; memset node is
    // graph-capturable.
    hipMemsetAsync(out, 0, sizeof(float), stream);

    const int rows_per_block = 4;  // one row per wave
    const int grid = BATCH / rows_per_block;  // 4096
    cbow_loss_kernel<<<grid, 256, 0, stream>>>(
        pos_target, pos_contexts, pos_negatives, context_table, output_table, out);
}

// Round 7
// 156.218 us; speedup vs baseline: 1.0987x; 1.0987x over previous
//
#include <hip/hip_runtime.h>
#include <math.h>

#define VOCAB 100000
#define EMB   128
#define BATCH 16384
#define CTX   20
#define NEG   20
#define NSCORE (NEG + 1)   // target + negatives
#define NROWS  (CTX + NSCORE)  // 41 staged rows
#define SLOTS  (NROWS + 1)     // +1 dummy slot for the odd DMA half

// address-space casts for global_load_lds
#define AS3(p)  ((__attribute__((address_space(3))) void*)(p))
#define AS1C(p) ((const __attribute__((address_space(1))) void*)(p))

// softplus(x) = log(1+exp(x)) via raw v_exp_f32/v_log_f32.
// abs err ~1e-5 vs the 0.29 absolute threshold.
__device__ __forceinline__ float fast_softplus(float x) {
    return __logf(1.0f + __expf(x));
}

// 64-lane sum via DPP in the VALU pipe (LDS pipe stays free for ds_read).
// old=0 + bound_ctrl=1 => invalid source lanes contribute 0.
// Result is valid in lane 63 only.
__device__ __forceinline__ float wave_sum_dpp(float x) {
#define DPP_ADD(ctrl)                                                      \
    x += __int_as_float(__builtin_amdgcn_update_dpp(                       \
        0, __float_as_int(x), (ctrl), 0xf, 0xf, true));
    DPP_ADD(0x111)  // row_shr:1
    DPP_ADD(0x112)  // row_shr:2
    DPP_ADD(0x114)  // row_shr:4
    DPP_ADD(0x118)  // row_shr:8   -> lane15 of each row16 = row sum
    DPP_ADD(0x142)  // row_bcast:15 -> lane31 = rows0+1, lane63 partial
    DPP_ADD(0x143)  // row_bcast:31 -> lane63 = full 64-lane sum
#undef DPP_ADD
    return x;
}

__global__ __launch_bounds__(64) void cbow_stage_kernel(
    const int*   __restrict__ pos_target,     // [B]
    const int*   __restrict__ pos_contexts,   // [B, C]
    const int*   __restrict__ pos_negatives,  // [B, N]
    const float* __restrict__ context_table,  // [VOCAB, 128]
    const float* __restrict__ output_table,   // [VOCAB, 128]
    float*       __restrict__ partial)        // [B] per-row losses
{
    __shared__ __align__(1024) float smem[SLOTS * EMB];  // 21504 B -> 7 blocks/CU
    const int lane = threadIdx.x;      // one wave per block
    const int row  = blockIdx.x;       // one batch row per wave (uniform)

    // ---- indices: wave-uniform addresses -> scalar s_load into SGPRs ----
    int idx[SLOTS];
#pragma unroll
    for (int c = 0; c < CTX; ++c) idx[c] = pos_contexts[row * CTX + c];
    idx[CTX] = pos_target[row];
#pragma unroll
    for (int n = 0; n < NEG; ++n) idx[CTX + 1 + n] = pos_negatives[row * NEG + n];
    idx[NROWS] = idx[NROWS - 1];  // dummy slot

    // ---- stage all 41 rows via LDS-DMA: 21 instructions, zero data VGPRs.
    //      inst k: lanes 0-31 fetch row 2k, lanes 32-63 fetch row 2k+1,
    //      each lane 16 B; lands at smem + k*1024 + lane*16 => row r at
    //      smem + r*512. Rows 0..19 ctx table, 20..41 output table; the
    //      table switch falls exactly on the k=10 boundary. ----
#pragma unroll
    for (int k = 0; k < 21; ++k) {
        const char* tab = (2 * k < CTX) ? (const char*)context_table
                                        : (const char*)output_table;
        const long long ia = idx[2 * k];
        const long long ib = idx[2 * k + 1];
        const long long isel = (lane < 32) ? ia : ib;
        const char* g = tab + isel * 512 + (long long)(lane & 31) * 16;
        __builtin_amdgcn_global_load_lds(AS1C(g), AS3((char*)smem + k * 1024),
                                         16, 0, 0);
    }

    // ---- context sum: rows 0..19 done after the first 10 DMAs; the 11
    //      score DMAs keep flying while we sum. ----
    __asm__ volatile("s_waitcnt vmcnt(11)" ::: "memory");
    const float2* sm2 = (const float2*)smem;   // row r at r*64 + lane
    float2 acc = make_float2(0.f, 0.f);
#pragma unroll
    for (int c = 0; c < CTX; ++c) {
        const float2 v = sm2[c * 64 + lane];
        acc.x += v.x; acc.y += v.y;
    }

    // ---- 21 score dots; DPP reduction (VALU pipe); broadcast lane 63 via
    //      __shfl and accumulate softplus wave-uniformly ----
    __asm__ volatile("s_waitcnt vmcnt(0)" ::: "memory");
    float loss = 0.f;
#pragma unroll
    for (int n = 0; n < NSCORE; ++n) {
        const float2 s = sm2[(CTX + n) * 64 + lane];
        float p = fmaf(acc.x, s.x, acc.y * s.y);
        float tot = wave_sum_dpp(p);            // lane 63 holds score n
        float sc = __shfl(tot, 63);             // broadcast to all lanes
        sc = fminf(fmaxf(sc, -10.f), 10.f);
        loss += (n == 0) ? fast_softplus(-sc) : fast_softplus(sc);
    }
    if (lane == 0) partial[row] = loss;

}

__global__ __launch_bounds__(1024) void cbow_reduce_kernel(
    const float* __restrict__ partial, float* __restrict__ out)
{
    const int tid = threadIdx.x;
    float s = 0.f;
#pragma unroll
    for (int i = 0; i < BATCH / 1024; ++i) s += partial[tid + i * 1024];
    s = wave_sum_dpp(s);               // lane 63 of each wave
    __shared__ float sw[16];
    if ((tid & 63) == 63) sw[tid >> 6] = s;
    __syncthreads();
    if (tid == 0) {
        float t = 0.f;
#pragma unroll
        for (int i = 0; i < 16; ++i) t += sw[i];
        out[0] = t * (1.0f / (float)BATCH);   // full overwrite: no memset needed
    }
}

extern "C" void kernel_launch(void* const* d_in, const int* in_sizes, int n_in,
                              void* d_out, int out_size, void* d_ws, size_t ws_size,
                              hipStream_t stream) {
    const int*   pos_target    = (const int*)d_in[0];
    const int*   pos_contexts  = (const int*)d_in[1];
    const int*   pos_negatives = (const int*)d_in[2];
    const float* context_table = (const float*)d_in[3];
    const float* output_table  = (const float*)d_in[4];
    float* out     = (float*)d_out;
    float* partial = (float*)d_ws;     // 16384 floats = 64 KB scratch

    cbow_stage_kernel<<<BATCH, 64, 0, stream>>>(
        pos_target, pos_contexts, pos_negatives, context_table, output_table,
        partial);
    cbow_reduce_kernel<<<1, 1024, 0, stream>>>(partial, out);
}